// Round 13
// baseline (504.806 us; speedup 1.0000x reference)
//
#include <hip/hip_runtime.h>

// Round 13: gathers fused into conv kernels — each conv block gathers its own
// 128 node-rows straight into a 136-pitch LDS bf16 tile (no agg tensors in
// global, -46MB L3 traffic, 8->6 dispatches; gather blocks overlap conv
// blocks m114-style). Pitch 136: 16B-aligned b128 A-reads, 2-way bank alias
// (free, m136). CSR build (prep/scan/fill) unchanged from r12.

typedef unsigned short u16;
typedef unsigned int u32;
typedef __attribute__((ext_vector_type(8))) short bf16x8;
typedef __attribute__((ext_vector_type(4))) float f32x4;

__device__ __forceinline__ float bf2f(u16 h) {
    union { u32 u; float f; } v; v.u = ((u32)h) << 16; return v.f;
}
__device__ __forceinline__ u16 f2bf(float f) {
    union { float f; u32 u; } v; v.f = f;
    u32 lsb = (v.u >> 16) & 1u;
    v.u += 0x7fffu + lsb;           // RNE
    return (u16)(v.u >> 16);
}

// ---------------- prep megakernel: hist | xm->bf16 | xd->bf16 | wfrag --------
__global__ __launch_bounds__(256)
void prep_kernel(const int* __restrict__ dst_m, const int* __restrict__ dst_b,
                 int* __restrict__ deg_m, int* __restrict__ deg_b,
                 int* __restrict__ rank_m, int* __restrict__ rank_b, int E,
                 const float* __restrict__ xm, u16* __restrict__ xm_bf, int n8m,
                 const float* __restrict__ xd, u16* __restrict__ xd_bf, int n8d,
                 const float* __restrict__ w0, const float* __restrict__ w1,
                 const float* __restrict__ w2, const float* __restrict__ w3,
                 const float* __restrict__ w4, const float* __restrict__ w5,
                 const float* __restrict__ w6, u16* __restrict__ wbuf,
                 int HB, int TB, int TB2)
{
    const int b = blockIdx.x;
    if (b < HB) {
        int t = b * 256 + threadIdx.x;
        if (t < E) {
            rank_m[t] = atomicAdd(&deg_m[dst_m[t]], 1);
        } else if (t < 2 * E) {
            int e = t - E;
            rank_b[e] = atomicAdd(&deg_b[dst_b[e]], 1);
        }
    } else if (b < HB + TB + TB2) {
        const bool isM = b < HB + TB;
        const float* src = isM ? xm : xd;
        u16* dst = isM ? xm_bf : xd_bf;
        int n8 = isM ? n8m : n8d;
        int i = (b - (isM ? HB : HB + TB)) * 256 + threadIdx.x;
        if (i >= n8) return;
        float4 a = ((const float4*)src)[2 * i];
        float4 c = ((const float4*)src)[2 * i + 1];
        ushort4 h0; h0.x = f2bf(a.x); h0.y = f2bf(a.y); h0.z = f2bf(a.z); h0.w = f2bf(a.w);
        ushort4 h1; h1.x = f2bf(c.x); h1.y = f2bf(c.y); h1.z = f2bf(c.z); h1.w = f2bf(c.w);
        ((ushort4*)dst)[2 * i]     = h0;
        ((ushort4*)dst)[2 * i + 1] = h1;
    } else {
        int bb = b - HB - TB - TB2;
        const int widx = bb >> 6;
        const int o    = ((bb & 63) << 8) + threadIdx.x;
        const int OC   = (widx == 6) ? 64 : 128;
        if (o >= OC * 128) return;
        const float* W;
        switch (widx) {
            case 0: W = w0; break; case 1: W = w1; break; case 2: W = w2; break;
            case 3: W = w3; break; case 4: W = w4; break; case 5: W = w5; break;
            default: W = w6;
        }
        int j = o & 7;
        int lane = (o >> 3) & 63;
        int n, c;
        if (OC == 128) { n = (o >> 9) & 7; c = o >> 12; }
        else           { n = (o >> 9) & 3; c = o >> 11; }
        int col = n * 16 + (lane & 15);
        int k   = c * 32 + (lane >> 4) * 8 + j;
        wbuf[widx * 16384 + o] = f2bf(W[k * OC + col]);
    }
}

__device__ __forceinline__ int wave_incl_scan(int v, int lane) {
#pragma unroll
    for (int off = 1; off < 64; off <<= 1) {
        int t = __shfl_up(v, off, 64);
        if (lane >= off) v += t;
    }
    return v;
}

// exclusive scan + sentinel, 4 elems/thread
__global__ __launch_bounds__(1024)
void scan2_kernel(const int* __restrict__ degA, int* __restrict__ rpA, int nA,
                  const int* __restrict__ degB, int* __restrict__ rpB, int nB)
{
    const int* deg = blockIdx.x ? degB : degA;
    int* rp = blockIdx.x ? rpB : rpA;
    int n = blockIdx.x ? nB : nA;

    __shared__ int wsum[16];
    __shared__ int carry;
    const int tid = threadIdx.x, lane = tid & 63, wid = tid >> 6;
    if (tid == 0) carry = 0;
    __syncthreads();

    for (int base = 0; base < n; base += 4096) {
        int idx = base + tid * 4;
        int4 v = make_int4(0, 0, 0, 0);
        if (idx + 3 < n) v = *(const int4*)(deg + idx);
        else {
            if (idx + 0 < n) v.x = deg[idx + 0];
            if (idx + 1 < n) v.y = deg[idx + 1];
            if (idx + 2 < n) v.z = deg[idx + 2];
            if (idx + 3 < n) v.w = deg[idx + 3];
        }
        int s = v.x + v.y + v.z + v.w;
        int incl = wave_incl_scan(s, lane);
        if (lane == 63) wsum[wid] = incl;
        __syncthreads();
        if (wid == 0) {
            int t = (lane < 16) ? wsum[lane] : 0;
            int ti = wave_incl_scan(t, lane);
            if (lane < 16) wsum[lane] = ti - t;
        }
        __syncthreads();
        int base_t = carry + wsum[wid] + incl - s;
        if (idx + 3 < n) {
            int4 st;
            st.x = base_t;
            st.y = base_t + v.x;
            st.z = base_t + v.x + v.y;
            st.w = base_t + v.x + v.y + v.z;
            *(int4*)(rp + idx) = st;
        } else {
            if (idx + 0 < n) rp[idx + 0] = base_t;
            if (idx + 1 < n) rp[idx + 1] = base_t + v.x;
            if (idx + 2 < n) rp[idx + 2] = base_t + v.x + v.y;
            if (idx + 3 < n) rp[idx + 3] = base_t + v.x + v.y + v.z;
        }
        __syncthreads();
        if (tid == 1023) carry += wsum[15] + incl;
        __syncthreads();
    }
    if (tid == 0) rp[n] = carry;
}

// ---------------- atomic-free fill ----------------
__global__ __launch_bounds__(256)
void fill_kernel(const int* __restrict__ src_m, const int* __restrict__ dst_m,
                 const int* __restrict__ src_b, const int* __restrict__ dst_b,
                 const float* __restrict__ edge_w,
                 const int* __restrict__ rp_m, const int* __restrict__ rp_b,
                 const int* __restrict__ rank_m, const int* __restrict__ rank_b,
                 int* __restrict__ srcs_m, int2* __restrict__ edges_b, int E)
{
    int t = blockIdx.x * 256 + threadIdx.x;
    if (t < E) {
        int pos = rp_m[dst_m[t]] + rank_m[t];
        srcs_m[pos] = src_m[t];
    } else if (t < 2 * E) {
        int e = t - E;
        int pos = rp_b[dst_b[e]] + rank_b[e];
        float x = edge_w[e];
        int2 pk;
        pk.x = src_b[e];
        pk.y = __float_as_int(1.0f / (1.0f + __expf(-x)));
        edges_b[pos] = pk;
    }
}

// ---------------- gather 128 node-rows into LDS tile (pitch 136) ----------
// half-wave per node, 16 nodes per half-wave; out-of-range rows zero-filled.
template<bool WEIGHTED>
__device__ __forceinline__ void gather_tile(
    const u16* __restrict__ Xb, const int* __restrict__ srcs,
    const int2* __restrict__ edges, const int* __restrict__ rp,
    u16* tile, int rowbase, int N, int tid)
{
    const int hw = tid >> 5;
    const int cl = tid & 31;
    for (int t = 0; t < 16; ++t) {
        const int ln = hw * 16 + t;
        const int g = rowbase + ln;
        float4 acc = make_float4(0.f, 0.f, 0.f, 0.f);
        if (g < N) {
            int i = rp[g], end = rp[g + 1];
            for (; i + 4 <= end; i += 4) {
                int s0, s1, s2, s3;
                float w0 = 1.f, w1 = 1.f, w2 = 1.f, w3 = 1.f;
                if (WEIGHTED) {
                    int2 p0 = edges[i],     p1 = edges[i + 1];
                    int2 p2 = edges[i + 2], p3 = edges[i + 3];
                    s0 = p0.x; w0 = __int_as_float(p0.y);
                    s1 = p1.x; w1 = __int_as_float(p1.y);
                    s2 = p2.x; w2 = __int_as_float(p2.y);
                    s3 = p3.x; w3 = __int_as_float(p3.y);
                } else {
                    s0 = srcs[i]; s1 = srcs[i + 1]; s2 = srcs[i + 2]; s3 = srcs[i + 3];
                }
                ushort4 v0 = *(const ushort4*)(Xb + (size_t)s0 * 128 + cl * 4);
                ushort4 v1 = *(const ushort4*)(Xb + (size_t)s1 * 128 + cl * 4);
                ushort4 v2 = *(const ushort4*)(Xb + (size_t)s2 * 128 + cl * 4);
                ushort4 v3 = *(const ushort4*)(Xb + (size_t)s3 * 128 + cl * 4);
                acc.x = fmaf(w0, bf2f(v0.x), acc.x); acc.y = fmaf(w0, bf2f(v0.y), acc.y);
                acc.z = fmaf(w0, bf2f(v0.z), acc.z); acc.w = fmaf(w0, bf2f(v0.w), acc.w);
                acc.x = fmaf(w1, bf2f(v1.x), acc.x); acc.y = fmaf(w1, bf2f(v1.y), acc.y);
                acc.z = fmaf(w1, bf2f(v1.z), acc.z); acc.w = fmaf(w1, bf2f(v1.w), acc.w);
                acc.x = fmaf(w2, bf2f(v2.x), acc.x); acc.y = fmaf(w2, bf2f(v2.y), acc.y);
                acc.z = fmaf(w2, bf2f(v2.z), acc.z); acc.w = fmaf(w2, bf2f(v2.w), acc.w);
                acc.x = fmaf(w3, bf2f(v3.x), acc.x); acc.y = fmaf(w3, bf2f(v3.y), acc.y);
                acc.z = fmaf(w3, bf2f(v3.z), acc.z); acc.w = fmaf(w3, bf2f(v3.w), acc.w);
            }
            for (; i < end; ++i) {
                int s; float w = 1.f;
                if (WEIGHTED) { int2 pk = edges[i]; s = pk.x; w = __int_as_float(pk.y); }
                else s = srcs[i];
                ushort4 v = *(const ushort4*)(Xb + (size_t)s * 128 + cl * 4);
                acc.x = fmaf(w, bf2f(v.x), acc.x); acc.y = fmaf(w, bf2f(v.y), acc.y);
                acc.z = fmaf(w, bf2f(v.z), acc.z); acc.w = fmaf(w, bf2f(v.w), acc.w);
            }
        }
        ushort4 st;
        st.x = f2bf(acc.x); st.y = f2bf(acc.y);
        st.z = f2bf(acc.z); st.w = f2bf(acc.w);
        *(ushort4*)(tile + ln * 136 + cl * 4) = st;
    }
}

// ---------------- fused gather + conv1+conv2 ----------------
// seg1 (blocks < cb1): movie = relu(gather_m(xm_bf)@W1r + b1 + xm_bf@W1o)
// seg2: t2 = relu(gather_b(xm_bf)@W2r + b2 + xd_bf@W2o)
__global__ __launch_bounds__(256)
void gconv12(const u16* __restrict__ xm_bf, const u16* __restrict__ xd_bf,
             const int* __restrict__ srcs_m, const int2* __restrict__ edges_b,
             const int* __restrict__ rp_m, const int* __restrict__ rp_b,
             const u16* __restrict__ w1r, const u16* __restrict__ w1o,
             const float* __restrict__ b1, u16* __restrict__ movie, int N1, int cb1,
             const u16* __restrict__ w2r, const u16* __restrict__ w2o,
             const float* __restrict__ b2, u16* __restrict__ t2, int N2)
{
    __shared__ u16 tile[17408];   // 128 x 136 bf16 (34 KB)
    __shared__ u16 sW[16384];     // one W phase (32 KB)

    const bool seg1 = (int)blockIdx.x < cb1;
    const u16 *root, *Wr, *Wo; const float* bias; u16* C; int N, rowbase;
    if (seg1) { root = xm_bf; Wr = w1r; Wo = w1o; bias = b1; C = movie; N = N1; rowbase = blockIdx.x * 128; }
    else      { root = xd_bf; Wr = w2r; Wo = w2o; bias = b2; C = t2;    N = N2; rowbase = (blockIdx.x - cb1) * 128; }

    const int tid = threadIdx.x;
    for (int i = tid; i < 2048; i += 256)
        ((uint4*)sW)[i] = ((const uint4*)Wr)[i];
    if (seg1) gather_tile<false>(xm_bf, srcs_m, nullptr, rp_m, tile, rowbase, N, tid);
    else      gather_tile<true >(xm_bf, nullptr, edges_b, rp_b, tile, rowbase, N, tid);
    __syncthreads();

    const int lane = tid & 63;
    const int wv   = tid >> 6;
    const int lr   = lane & 15;
    const int quad = lane >> 4;
    const int r0l  = wv * 32 + lr;
    const int r1l  = wv * 32 + 16 + lr;

    f32x4 acc[2][8];
#pragma unroll
    for (int mt = 0; mt < 2; ++mt)
#pragma unroll
        for (int n = 0; n < 8; ++n) acc[mt][n] = (f32x4){0.f, 0.f, 0.f, 0.f};

    // phase 0: aggregate term, A from LDS tile
#pragma unroll
    for (int c = 0; c < 4; ++c) {
        const int kb = c * 32 + quad * 8;
        bf16x8 a0 = *(const bf16x8*)(tile + r0l * 136 + kb);
        bf16x8 a1 = *(const bf16x8*)(tile + r1l * 136 + kb);
        const u16* wp = sW + c * 4096 + lane * 8;
#pragma unroll
        for (int n = 0; n < 8; ++n) {
            bf16x8 b = *(const bf16x8*)(wp + n * 512);
            acc[0][n] = __builtin_amdgcn_mfma_f32_16x16x32_bf16(a0, b, acc[0][n], 0, 0, 0);
            acc[1][n] = __builtin_amdgcn_mfma_f32_16x16x32_bf16(a1, b, acc[1][n], 0, 0, 0);
        }
    }
    __syncthreads();
    for (int i = tid; i < 2048; i += 256)
        ((uint4*)sW)[i] = ((const uint4*)Wo)[i];
    __syncthreads();

    // phase 1: root term, A from global bf16 rows (clamped)
    int g0 = rowbase + r0l; if (g0 >= N) g0 = N - 1;
    int g1 = rowbase + r1l; if (g1 >= N) g1 = N - 1;
#pragma unroll
    for (int c = 0; c < 4; ++c) {
        const int kb = c * 32 + quad * 8;
        bf16x8 a0 = *(const bf16x8*)(root + (size_t)g0 * 128 + kb);
        bf16x8 a1 = *(const bf16x8*)(root + (size_t)g1 * 128 + kb);
        const u16* wp = sW + c * 4096 + lane * 8;
#pragma unroll
        for (int n = 0; n < 8; ++n) {
            bf16x8 b = *(const bf16x8*)(wp + n * 512);
            acc[0][n] = __builtin_amdgcn_mfma_f32_16x16x32_bf16(a0, b, acc[0][n], 0, 0, 0);
            acc[1][n] = __builtin_amdgcn_mfma_f32_16x16x32_bf16(a1, b, acc[1][n], 0, 0, 0);
        }
    }

#pragma unroll
    for (int mt = 0; mt < 2; ++mt) {
#pragma unroll
        for (int n = 0; n < 8; ++n) {
            const int col = n * 16 + lr;
            const float b = bias[col];
#pragma unroll
            for (int r = 0; r < 4; ++r) {
                int row = rowbase + wv * 32 + mt * 16 + quad * 4 + r;
                if (row >= N) continue;
                C[(size_t)row * 128 + col] = f2bf(fmaxf(acc[mt][n][r] + b, 0.f));
            }
        }
    }
}

// ---------------- fused gather3 + conv3 + lin ----------------
// out = (relu(gather_b(movie)@W3r + b3 + t2@W3o)) @ Wl + bl
__global__ __launch_bounds__(256)
void gconv3lin(const u16* __restrict__ movie, const u16* __restrict__ t2,
               const int2* __restrict__ edges_b, const int* __restrict__ rp_b,
               const u16* __restrict__ w3r, const u16* __restrict__ w3o,
               const float* __restrict__ bias3,
               const u16* __restrict__ wl, const float* __restrict__ bias_l,
               float* __restrict__ out, int N)
{
    __shared__ u16 tile[17408];   // 34 KB: gather tile, later result tile
    __shared__ u16 sW[16384];     // 32 KB: w3r -> w3o -> wl

    const int tid = threadIdx.x;
    const int rowbase = blockIdx.x * 128;

    for (int i = tid; i < 2048; i += 256)
        ((uint4*)sW)[i] = ((const uint4*)w3r)[i];
    gather_tile<true>(movie, nullptr, edges_b, rp_b, tile, rowbase, N, tid);
    __syncthreads();

    const int lane = tid & 63;
    const int wv   = tid >> 6;
    const int lr   = lane & 15;
    const int quad = lane >> 4;
    const int r0l  = wv * 32 + lr;
    const int r1l  = wv * 32 + 16 + lr;

    f32x4 acc[2][8];
#pragma unroll
    for (int mt = 0; mt < 2; ++mt)
#pragma unroll
        for (int n = 0; n < 8; ++n) acc[mt][n] = (f32x4){0.f, 0.f, 0.f, 0.f};

#pragma unroll
    for (int c = 0; c < 4; ++c) {
        const int kb = c * 32 + quad * 8;
        bf16x8 a0 = *(const bf16x8*)(tile + r0l * 136 + kb);
        bf16x8 a1 = *(const bf16x8*)(tile + r1l * 136 + kb);
        const u16* wp = sW + c * 4096 + lane * 8;
#pragma unroll
        for (int n = 0; n < 8; ++n) {
            bf16x8 b = *(const bf16x8*)(wp + n * 512);
            acc[0][n] = __builtin_amdgcn_mfma_f32_16x16x32_bf16(a0, b, acc[0][n], 0, 0, 0);
            acc[1][n] = __builtin_amdgcn_mfma_f32_16x16x32_bf16(a1, b, acc[1][n], 0, 0, 0);
        }
    }
    __syncthreads();
    for (int i = tid; i < 2048; i += 256)
        ((uint4*)sW)[i] = ((const uint4*)w3o)[i];
    __syncthreads();

    int g0 = rowbase + r0l; if (g0 >= N) g0 = N - 1;
    int g1 = rowbase + r1l; if (g1 >= N) g1 = N - 1;
#pragma unroll
    for (int c = 0; c < 4; ++c) {
        const int kb = c * 32 + quad * 8;
        bf16x8 a0 = *(const bf16x8*)(t2 + (size_t)g0 * 128 + kb);
        bf16x8 a1 = *(const bf16x8*)(t2 + (size_t)g1 * 128 + kb);
        const u16* wp = sW + c * 4096 + lane * 8;
#pragma unroll
        for (int n = 0; n < 8; ++n) {
            bf16x8 b = *(const bf16x8*)(wp + n * 512);
            acc[0][n] = __builtin_amdgcn_mfma_f32_16x16x32_bf16(a0, b, acc[0][n], 0, 0, 0);
            acc[1][n] = __builtin_amdgcn_mfma_f32_16x16x32_bf16(a1, b, acc[1][n], 0, 0, 0);
        }
    }
    __syncthreads();   // done reading tile (p0) and w3o; overlay both

    // relu'd bf16 result tile (C-layout -> padded rows) + stage lin W
#pragma unroll
    for (int mt = 0; mt < 2; ++mt) {
#pragma unroll
        for (int n = 0; n < 8; ++n) {
            const int col = n * 16 + lr;
            const float b = bias3[col];
#pragma unroll
            for (int r = 0; r < 4; ++r) {
                int row = wv * 32 + mt * 16 + quad * 4 + r;
                tile[row * 136 + col] = f2bf(fmaxf(acc[mt][n][r] + b, 0.f));
            }
        }
    }
    for (int i = tid; i < 1024; i += 256)
        ((uint4*)sW)[i] = ((const uint4*)wl)[i];
    __syncthreads();

    f32x4 acc2[2][4];
#pragma unroll
    for (int mt = 0; mt < 2; ++mt)
#pragma unroll
        for (int n = 0; n < 4; ++n) acc2[mt][n] = (f32x4){0.f, 0.f, 0.f, 0.f};

#pragma unroll
    for (int c = 0; c < 4; ++c) {
        const int kb = c * 32 + quad * 8;
        bf16x8 a0 = *(const bf16x8*)(tile + r0l * 136 + kb);
        bf16x8 a1 = *(const bf16x8*)(tile + r1l * 136 + kb);
#pragma unroll
        for (int n = 0; n < 4; ++n) {
            bf16x8 b = *(const bf16x8*)(sW + c * 2048 + n * 512 + lane * 8);
            acc2[0][n] = __builtin_amdgcn_mfma_f32_16x16x32_bf16(a0, b, acc2[0][n], 0, 0, 0);
            acc2[1][n] = __builtin_amdgcn_mfma_f32_16x16x32_bf16(a1, b, acc2[1][n], 0, 0, 0);
        }
    }

#pragma unroll
    for (int mt = 0; mt < 2; ++mt) {
#pragma unroll
        for (int n = 0; n < 4; ++n) {
            const int col = n * 16 + lr;
            const float b = bias_l[col];
#pragma unroll
            for (int r = 0; r < 4; ++r) {
                int row = rowbase + wv * 32 + mt * 16 + quad * 4 + r;
                if (row >= N) continue;
                out[(size_t)row * 64 + col] = acc2[mt][n][r] + b;
            }
        }
    }
}

extern "C" void kernel_launch(void* const* d_in, const int* in_sizes, int n_in,
                              void* d_out, int out_size, void* d_ws, size_t ws_size,
                              hipStream_t stream)
{
    const float* x_meas  = (const float*)d_in[0];
    const float* x_dem   = (const float*)d_in[1];
    const int*   src_m   = (const int*)d_in[2];
    const int*   dst_m   = (const int*)d_in[3];
    const int*   src_b   = (const int*)d_in[4];
    const int*   dst_b   = (const int*)d_in[5];
    const float* edge_w  = (const float*)d_in[6];
    const float* W_rel1  = (const float*)d_in[7];
    const float* b_rel1  = (const float*)d_in[8];
    const float* W_root1 = (const float*)d_in[9];
    const float* W_rel2  = (const float*)d_in[10];
    const float* b_rel2  = (const float*)d_in[11];
    const float* W_root2 = (const float*)d_in[12];
    const float* W_rel3  = (const float*)d_in[13];
    const float* b_rel3  = (const float*)d_in[14];
    const float* W_root3 = (const float*)d_in[15];
    const float* W_lin   = (const float*)d_in[16];
    const float* b_lin   = (const float*)d_in[17];
    float* out = (float*)d_out;

    const int NM = 50000, ND = 20000, E = 600000;

    char* p = (char*)d_ws;
    auto alloc = [&](size_t bytes) { char* r = p; p += (bytes + 511) & ~(size_t)511; return r; };
    int*   deg_m   = (int*)alloc((size_t)NM * 4);
    int*   deg_b   = (int*)alloc((size_t)ND * 4);
    int*   rp_m    = (int*)alloc((size_t)(NM + 1) * 4);
    int*   rp_b    = (int*)alloc((size_t)(ND + 1) * 4);
    int*   srcs_m  = (int*)alloc((size_t)E * 4);
    int2*  edges_b = (int2*)alloc((size_t)E * 8);
    u16*   xm_bf   = (u16*)alloc((size_t)NM * 128 * 2);   // 12.8 MB
    u16*   xd_bf   = (u16*)alloc((size_t)ND * 128 * 2);   // 5.12 MB
    u16*   movie   = (u16*)alloc((size_t)NM * 128 * 2);   // 12.8 MB
    u16*   t2      = (u16*)alloc((size_t)ND * 128 * 2);   // 5.12 MB
    u16*   wbuf    = (u16*)alloc(7 * 16384 * 2);          // 224 KB
    // ranks alias movie (ranks die at fill; movie first written by gconv12)
    int* rank_m = (int*)movie;
    int* rank_b = rank_m + E;

    size_t deg_span = (size_t)((char*)deg_b - (char*)deg_m) + (size_t)ND * 4;
    hipMemsetAsync(deg_m, 0, deg_span, stream);

    const int HB  = (2 * E + 255) / 256;       // 4688
    const int TB  = (NM * 16 + 255) / 256;     // 3125
    const int TB2 = (ND * 16 + 255) / 256;     // 1250
    const int WB  = 448;
    prep_kernel<<<HB + TB + TB2 + WB, 256, 0, stream>>>(
        dst_m, dst_b, deg_m, deg_b, rank_m, rank_b, E,
        x_meas, xm_bf, NM * 16, x_dem, xd_bf, ND * 16,
        W_rel1, W_root1, W_rel2, W_root2, W_rel3, W_root3, W_lin, wbuf,
        HB, TB, TB2);

    scan2_kernel<<<2, 1024, 0, stream>>>(deg_m, rp_m, NM, deg_b, rp_b, ND);
    fill_kernel<<<HB, 256, 0, stream>>>(src_m, dst_m, src_b, dst_b, edge_w,
                                        rp_m, rp_b, rank_m, rank_b, srcs_m, edges_b, E);

    const int cb1 = (NM + 127) / 128;   // 391
    const int cb2 = (ND + 127) / 128;   // 157
    u16* w1r = wbuf + 0 * 16384; u16* w1o = wbuf + 1 * 16384;
    u16* w2r = wbuf + 2 * 16384; u16* w2o = wbuf + 3 * 16384;
    u16* w3r = wbuf + 4 * 16384; u16* w3o = wbuf + 5 * 16384;
    u16* wl  = wbuf + 6 * 16384;

    gconv12<<<cb1 + cb2, 256, 0, stream>>>(xm_bf, xd_bf, srcs_m, edges_b, rp_m, rp_b,
                                           w1r, w1o, b_rel1, movie, NM, cb1,
                                           w2r, w2o, b_rel2, t2, ND);

    gconv3lin<<<cb2, 256, 0, stream>>>(movie, t2, edges_b, rp_b,
                                       w3r, w3o, b_rel3, wl, b_lin, out, ND);
}